// Round 6
// baseline (199.890 us; speedup 1.0000x reference)
//
#include <hip/hip_runtime.h>
#include <hip/hip_fp16.h>

// PosteriorHiddenTreeMarkovModel — MI355X / gfx950
// R19 = 2-wave teams per subtree, packed fully resident (no dispatch rounds).
// Post-mortems: R18 ILP pairing spilled (VGPR 96->128, 33MB scratch traffic,
// 82.6->94.6us) — revert to R15 single-node bodies. R17 showed the 2-wave
// node-split itself may help but grid 1792 > resident 1280 caused rounds.
// Constraint analysis: total waves was 1728 (1/subtree) = 6.75/CU; VGPR~96
// caps at 16 waves/CU. This config doubles TLP within capacity:
//   - 864 subtree blocks: 256 thr = 2 teams x 2 waves; team = one subtree,
//     16 node-lanes/iteration => serial passes 26 -> 15 (up 8->5, dn 18->10).
//   - 32 mid blocks: 2 teams, each one tree's mid (levels 0-3), fp32 bMid
//     aliased into the team's bW record (no extra LDS).
//   - LDS ~38KB -> 4 blocks/CU; grid 896 <= 1024 capacity => ALL resident,
//     14 waves/CU (vs 7). __launch_bounds__(256,4) caps VGPR at 128.
// Bodies verbatim R15 (no pairing). bmG [g][m][c] vectorized rows; b3/e3
// [c][g] with same addresses as R15 (stale-launch idempotency preserved).
// Protocol unchanged: trCnt reset by block 0, trFlg stale-fast, spin-safe.

namespace {

constexpr int kNPT = 3280;
constexpr int kRS  = 72;   // subtree record stride: 64 beta + 8 pre-norm sums
constexpr int kAS  = 68;   // A row stride per (g,p)
constexpr int kSubBlocks = 864;
constexpr unsigned kMAGIC  = 0x13579BDFu;
constexpr unsigned kMAGIC2 = 0x2468ACEFu;
__device__ __constant__ int LO[6] = {0, 1, 4, 13, 40, 121};
__device__ __constant__ int P3[5] = {1, 3, 9, 27, 81};

#define AGENT_LD(p)    __hip_atomic_load((p), __ATOMIC_RELAXED, __HIP_MEMORY_SCOPE_AGENT)
#define AGENT_ST(p, v) __hip_atomic_store((p), (v), __ATOMIC_RELAXED, __HIP_MEMORY_SCOPE_AGENT)

// Load the 8-float Bm row for (g, xv): pBmg = bmG + g*1024, row at xv*8.
__device__ __forceinline__ void bm_row(const float* __restrict__ pBmg, int xv,
                                       float* m)
{
    const float4 r0 = *(const float4*)(pBmg + (xv << 3));
    const float4 r1 = *(const float4*)(pBmg + (xv << 3) + 4);
    m[0] = r0.x; m[1] = r0.y; m[2] = r0.z; m[3] = r0.w;
    m[4] = r1.x; m[5] = r1.y; m[6] = r1.z; m[7] = r1.w;
}

__device__ __forceinline__ void leaf_beta(const float* __restrict__ sPi,
                                          const float* __restrict__ pBmg,
                                          int p, int xv, int g, float* b)
{
    float m[8];
    bm_row(pBmg, xv, m);
    float s = 0.f;
    #pragma unroll
    for (int c = 0; c < 8; ++c) {
        b[c] = sPi[(c * 3 + p) * 8 + g] * m[c];
        s += b[c];
    }
    float ig = __builtin_amdgcn_rcpf(s);
    #pragma unroll
    for (int c = 0; c < 8; ++c) b[c] *= ig;
}

// acc[i] *= Bm row; returns pre-norm sum
__device__ __forceinline__ float norm_mul(const float* __restrict__ pBmg,
                                          int xv, float* acc)
{
    float m[8];
    bm_row(pBmg, xv, m);
    float s = 0.f;
    #pragma unroll
    for (int i = 0; i < 8; ++i) { acc[i] *= m[i]; s += acc[i]; }
    return s;
}

// acc[i] += (spg*bj[j]) * A[i][j] over j; A row via 2x b128 per j
__device__ __forceinline__ void matvec_acc(const float* __restrict__ arow,
                                           const float* __restrict__ bj,
                                           float spg, float* acc)
{
    #pragma unroll
    for (int j = 0; j < 8; ++j) {
        float4 a0 = *(const float4*)(arow + j * 8);
        float4 a1 = *(const float4*)(arow + j * 8 + 4);
        float cjv = spg * bj[j];
        acc[0] = fmaf(a0.x, cjv, acc[0]); acc[1] = fmaf(a0.y, cjv, acc[1]);
        acc[2] = fmaf(a0.z, cjv, acc[2]); acc[3] = fmaf(a0.w, cjv, acc[3]);
        acc[4] = fmaf(a1.x, cjv, acc[4]); acc[5] = fmaf(a1.y, cjv, acc[5]);
        acc[6] = fmaf(a1.z, cjv, acc[6]); acc[7] = fmaf(a1.w, cjv, acc[7]);
    }
}

// down-pass inner: ev[j] = spg*bj[j]*dot(r,A_j); lg += spg*bj[j]*dot(r,AlogA_j)
__device__ __forceinline__ void dn_body(const float* r, const float* bj, float spg,
                                        const float* __restrict__ arow,
                                        const float* __restrict__ lrow,
                                        float* ev, float& esum, float& lg)
{
    #pragma unroll
    for (int j = 0; j < 8; ++j) {
        float4 a0 = *(const float4*)(arow + j * 8);
        float4 a1 = *(const float4*)(arow + j * 8 + 4);
        float4 l0 = *(const float4*)(lrow + j * 8);
        float4 l1 = *(const float4*)(lrow + j * 8 + 4);
        float s1 = r[0] * a0.x; s1 = fmaf(r[1], a0.y, s1);
        s1 = fmaf(r[2], a0.z, s1); s1 = fmaf(r[3], a0.w, s1);
        s1 = fmaf(r[4], a1.x, s1); s1 = fmaf(r[5], a1.y, s1);
        s1 = fmaf(r[6], a1.z, s1); s1 = fmaf(r[7], a1.w, s1);
        float s2 = r[0] * l0.x; s2 = fmaf(r[1], l0.y, s2);
        s2 = fmaf(r[2], l0.z, s2); s2 = fmaf(r[3], l0.w, s2);
        s2 = fmaf(r[4], l1.x, s2); s2 = fmaf(r[5], l1.y, s2);
        s2 = fmaf(r[6], l1.z, s2); s2 = fmaf(r[7], l1.w, s2);
        float bs = spg * bj[j];
        ev[j] = bs * s1;
        lg    = fmaf(bs, s2, lg);
        esum += ev[j];
    }
}

__global__ __launch_bounds__(256, 4)
void fused(const float* __restrict__ lamA, const float* __restrict__ lamB,
           const float* __restrict__ lamPi, const float* __restrict__ lamSP,
           const int* __restrict__ x, float* __restrict__ out,
           unsigned* __restrict__ sy, float* __restrict__ bmG,
           float* __restrict__ b3, float* __restrict__ e3)
{
    const int tid = threadIdx.x, w = tid >> 6, lane = tid & 63;
    const int n = lane >> 3, g = lane & 7;
    const int team = w >> 1, wv = w & 1;
    const int vn = (wv << 3) + n;      // 16 node-lanes per team
    const int ttid = tid & 127;        // team-local tid
    __shared__ __align__(16) float sAg[24 * kAS];   // A    [g][p][j][i]
    __shared__ __align__(16) float sLAg[24 * kAS];  // AlogA same layout
    __shared__ float sPi[192], sLPi[192], sSP[24], sLSP[24];
    __shared__ float bW[2][40 * kRS];               // per-team subtree records
    __shared__ unsigned char xW[2][124];
    unsigned* trCnt = sy + 32;
    unsigned* trFlg = sy + 2080;

    // ---- init gate ----
    if (tid == 0) {
        if (blockIdx.x == 0) {
            for (int i = 0; i < 64; ++i) AGENT_ST(&trCnt[i * 32], 0u);
            __builtin_amdgcn_s_waitcnt(0);
            AGENT_ST(&sy[0], kMAGIC);
        }
        unsigned long sp = 0;
        while (AGENT_LD(&sy[0]) != kMAGIC) {
            if (++sp > (1UL << 24)) break;
            __builtin_amdgcn_s_sleep(2);
        }
    }
    __syncthreads();

    // ================= phase 0: parameters =================
    if (blockIdx.x == 0) {   // Bm softmax -> bmG [g][m][c] + flag
        float* rr = &bW[0][0];
        int row = tid >> 2, part = tid & 3;
        int c = row >> 3, gg = row & 7, m0 = part * 32;
        float mx = -1e30f;
        for (int mm = 0; mm < 32; ++mm)
            mx = fmaxf(mx, lamB[(c * 128 + m0 + mm) * 8 + gg]);
        rr[tid] = mx;
        __syncthreads();
        float m4 = fmaxf(fmaxf(rr[row * 4], rr[row * 4 + 1]),
                         fmaxf(rr[row * 4 + 2], rr[row * 4 + 3]));
        float s = 0.f;
        for (int mm = 0; mm < 32; ++mm)
            s += expf(lamB[(c * 128 + m0 + mm) * 8 + gg] - m4);
        rr[256 + tid] = s;
        __syncthreads();
        float stot = rr[256 + row * 4] + rr[256 + row * 4 + 1]
                   + rr[256 + row * 4 + 2] + rr[256 + row * 4 + 3];
        float inv = 1.f / stot;
        for (int mm = 0; mm < 32; ++mm)
            AGENT_ST(&bmG[(gg * 128 + m0 + mm) * 8 + c],
                     expf(lamB[(c * 128 + m0 + mm) * 8 + gg] - m4) * inv);
        __syncthreads();
        if (tid == 0) AGENT_ST(&sy[4], kMAGIC2);
    }
    for (int col = tid; col < 192; col += 256) {   // A softmax over i -> g-major
        int j = col / 24; int rem = col - j * 24; int p = rem >> 3; int gg = rem & 7;
        float v[8]; float mx = -1e30f;
        #pragma unroll
        for (int i = 0; i < 8; ++i) {
            v[i] = lamA[((i * 8 + j) * 3 + p) * 8 + gg];
            mx = fmaxf(mx, v[i]);
        }
        float s = 0.f;
        #pragma unroll
        for (int i = 0; i < 8; ++i) { v[i] = expf(v[i] - mx); s += v[i]; }
        float inv = 1.f / s;
        int base = (gg * 3 + p) * kAS + j * 8;
        #pragma unroll
        for (int i = 0; i < 8; ++i) {
            float sm = v[i] * inv;
            sAg[base + i]  = sm;
            sLAg[base + i] = sm * logf(sm);
        }
    }
    for (int col = tid; col < 24; col += 256) {    // Pi softmax over c
        int p = col >> 3; int gg = col & 7;
        float v[8]; float mx = -1e30f;
        #pragma unroll
        for (int c = 0; c < 8; ++c) {
            v[c] = lamPi[(c * 3 + p) * 8 + gg];
            mx = fmaxf(mx, v[c]);
        }
        float s = 0.f;
        #pragma unroll
        for (int c = 0; c < 8; ++c) { v[c] = expf(v[c] - mx); s += v[c]; }
        float inv = 1.f / s;
        #pragma unroll
        for (int c = 0; c < 8; ++c) {
            int idx = (c * 3 + p) * 8 + gg;
            float sm = v[c] * inv;
            sPi[idx]  = sm;
            sLPi[idx] = logf(sm);
        }
    }
    if (tid < 8) {                                 // SP softmax over p
        int gg = tid;
        float v0 = lamSP[gg], v1 = lamSP[8 + gg], v2 = lamSP[16 + gg];
        float mx = fmaxf(v0, fmaxf(v1, v2));
        float e0 = expf(v0 - mx), e1 = expf(v1 - mx), e2 = expf(v2 - mx);
        float inv = 1.f / (e0 + e1 + e2);
        sSP[gg] = e0 * inv; sSP[8 + gg] = e1 * inv; sSP[16 + gg] = e2 * inv;
        sLSP[gg] = logf(e0 * inv); sLSP[8 + gg] = logf(e1 * inv); sLSP[16 + gg] = logf(e2 * inv);
    }
    if (tid == 0) {        // Bm gate: one fence per block per launch
        unsigned long sp = 0;
        while (AGENT_LD(&sy[4]) != kMAGIC2) {
            if (++sp > (1UL << 24)) break;
            __builtin_amdgcn_s_sleep(2);
        }
        __threadfence();
    }
    __syncthreads();

    const float* pBmg = bmG + (g << 10);   // per-lane Bm row base [g][m][c]
    float* bw = &bW[team][0];

    if (blockIdx.x < kSubBlocks) {
        // ============ subtree block: 2 teams, each one subtree ============
        unsigned char* xw = &xW[team][0];
        const int sIdx = blockIdx.x * 2 + team;
        const int t = sIdx / 27, q = sIdx - t * 27;
        const int xb = t * kNPT;

        for (int u = ttid; u < 121; u += 128) {
            int gx;
            if (u == 0)       gx = 13 + q;
            else if (u < 4)   gx = 40  + q * 3  + (u - 1);
            else if (u < 13)  gx = 121 + q * 9  + (u - 4);
            else if (u < 40)  gx = 364 + q * 27 + (u - 13);
            else              gx = 1093 + q * 81 + (u - 40);
            xw[u] = (unsigned char)x[xb + gx];
        }
        __syncthreads();

        // ---- up-pass: 16 node-lanes per team ----
        for (int e = 3; e >= 0; --e) {
            int cnt = P3[e];
            for (int base = 0; base < cnt; base += 16) {
                int node = base + vn;
                if (node < cnt) {
                    float acc[8];
                    #pragma unroll
                    for (int i = 0; i < 8; ++i) acc[i] = 0.f;
                    #pragma unroll
                    for (int k = 0; k < 3; ++k) {
                        float bj[8];
                        if (e == 3) {
                            leaf_beta(sPi, pBmg, k, xw[40 + 3 * node + k], g, bj);
                        } else {
                            int co = (LO[e + 1] + 3 * node + k) * kRS + g;
                            #pragma unroll
                            for (int j = 0; j < 8; ++j) bj[j] = bw[co + j * 8];
                        }
                        matvec_acc(&sAg[(g * 3 + k) * kAS], bj, sSP[k * 8 + g], acc);
                    }
                    if (e == 0) {
                        #pragma unroll
                        for (int i = 0; i < 8; ++i) bw[i * 8 + g] = acc[i];  // raw tb root
                        float s = norm_mul(pBmg, xw[0], acc);
                        float ig = __builtin_amdgcn_rcpf(s);
                        #pragma unroll
                        for (int i = 0; i < 8; ++i)
                            AGENT_ST(&b3[sIdx * 64 + i * 8 + g], acc[i] * ig);
                    } else {
                        int slot = LO[e] + node;
                        float s = norm_mul(pBmg, xw[slot], acc);
                        float ig = __builtin_amdgcn_rcpf(s);
                        int bo = slot * kRS + g;
                        #pragma unroll
                        for (int i = 0; i < 8; ++i) bw[bo + i * 8] = acc[i] * ig;
                        bw[slot * kRS + 64 + g] = s;
                    }
                }
            }
            __syncthreads();
        }
        __builtin_amdgcn_s_waitcnt(0);
        if (ttid == 0)
            __hip_atomic_fetch_add(&trCnt[t * 32], 1u, __ATOMIC_RELAXED,
                                   __HIP_MEMORY_SCOPE_AGENT);

        // ---- wait for mid flag (stale-fast), then down-pass ----
        {
            unsigned long sp = 0;
            while (AGENT_LD(&trFlg[t * 32]) != kMAGIC2) {
                if (++sp > (1UL << 22)) break;
                __builtin_amdgcn_s_sleep(1);
            }
        }
        if (wv == 0)
            bw[lane] = AGENT_LD(&e3[sIdx * 64 + lane])
                       * __builtin_amdgcn_rcpf(bw[lane]);
        __syncthreads();

        float ell = 0.f;
        for (int e = 1; e <= 4; ++e) {
            int cnt = P3[e], pl0 = LO[e - 1];
            for (int base = 0; base < cnt; base += 16) {
                int ci = base + vn;
                if (ci < cnt) {
                    int p = ci % 3;
                    int ps = (pl0 + ci / 3) * kRS + g;
                    float r[8];
                    #pragma unroll
                    for (int i = 0; i < 8; ++i) r[i] = bw[ps + i * 8];
                    float bj[8], Bmv[8]; float sv = 0.f;
                    if (e == 4) {
                        bm_row(pBmg, xw[40 + ci], Bmv);   // one load, used twice
                        float s = 0.f;
                        #pragma unroll
                        for (int c = 0; c < 8; ++c) {
                            bj[c] = sPi[(c * 3 + p) * 8 + g] * Bmv[c];
                            s += bj[c];
                        }
                        float ig = __builtin_amdgcn_rcpf(s);
                        #pragma unroll
                        for (int c = 0; c < 8; ++c) bj[c] *= ig;
                    } else {
                        int slot = LO[e] + ci;
                        bm_row(pBmg, xw[slot], Bmv);
                        int co = slot * kRS + g;
                        #pragma unroll
                        for (int j = 0; j < 8; ++j) bj[j] = bw[co + j * 8];
                        sv = bw[slot * kRS + 64 + g];
                    }
                    float ev[8]; float esum = 0.f, lg = 0.f;
                    dn_body(r, bj, sSP[p * 8 + g],
                            &sAg[(g * 3 + p) * kAS], &sLAg[(g * 3 + p) * kAS],
                            ev, esum, lg);
                    lg = fmaf(esum, sLSP[p * 8 + g], lg);
                    #pragma unroll
                    for (int c = 0; c < 8; ++c) lg = fmaf(ev[c], Bmv[c], lg);
                    if (e < 4) {
                        int slot = LO[e] + ci;
                        int co = slot * kRS + g;
                        #pragma unroll
                        for (int j = 0; j < 8; ++j)
                            bw[co + j * 8] = ev[j] * Bmv[j]
                                * __builtin_amdgcn_rcpf(bj[j] * sv);
                    } else {
                        #pragma unroll
                        for (int c = 0; c < 8; ++c)
                            lg = fmaf(ev[c], sLPi[(c * 3 + p) * 8 + g], lg);
                    }
                    ell += lg;
                }
            }
            __syncthreads();
        }

        ell += __shfl_xor(ell, 8);
        ell += __shfl_xor(ell, 16);
        ell += __shfl_xor(ell, 32);
        if (n == 0) atomicAdd(&out[t * 8 + g], -ell);
        return;
    }

    // ============ mid block: 2 teams, each one tree's mid ============
    {
        const int tm = (blockIdx.x - kSubBlocks) * 2 + team;
        const int xb = tm * kNPT;
        float* bMid = bw;               // 13*64 fp32, aliased into record
        float* sMs  = bw + 13 * 64;     // 13*8 pre-norm sums

        {
            unsigned long sp = 0;
            while (AGENT_LD(&trCnt[tm * 32]) < 27u) {
                if (++sp > (1UL << 22)) break;
                __builtin_amdgcn_s_sleep(1);
            }
        }
        __threadfence();   // one invalidate; b3 then read via cached loads
        __syncthreads();

        float ellm = 0.f;

        for (int f = 2; f >= 0; --f) {     // ---- up: one pass per level ----
            int cnt = (f == 2) ? 9 : (f == 1 ? 3 : 1);
            int pl0 = (f == 2) ? 4 : (f == 1 ? 1 : 0);
            int cl0 = (f == 1) ? 4 : 1;
            int pi = vn;
            if (pi < cnt) {
                float acc[8];
                #pragma unroll
                for (int i = 0; i < 8; ++i) acc[i] = 0.f;
                #pragma unroll
                for (int k = 0; k < 3; ++k) {
                    float bj[8];
                    if (f == 2) {
                        const float* src = b3 + (tm * 27 + 3 * pi + k) * 64 + g;
                        #pragma unroll
                        for (int j = 0; j < 8; ++j) bj[j] = src[j * 8];
                    } else {
                        int co = (cl0 + 3 * pi + k) * 64 + g;
                        #pragma unroll
                        for (int j = 0; j < 8; ++j) bj[j] = bMid[co + j * 8];
                    }
                    matvec_acc(&sAg[(g * 3 + k) * kAS], bj, sSP[k * 8 + g], acc);
                }
                int slot = pl0 + pi;
                float s = norm_mul(pBmg, x[xb + slot], acc);
                float ig = __builtin_amdgcn_rcpf(s);
                int bo = slot * 64 + g;
                #pragma unroll
                for (int i = 0; i < 8; ++i) bMid[bo + i * 8] = acc[i] * ig;
                sMs[slot * 8 + g] = s;
            }
            __syncthreads();
        }
        if (wv == 0 && n == 0) {   // root: ell Bm term; slot0 := r = Bm/s
            float m[8];
            bm_row(pBmg, x[xb], m);
            float invs = __builtin_amdgcn_rcpf(sMs[g]);
            #pragma unroll
            for (int c = 0; c < 8; ++c)
                ellm += bMid[c * 8 + g] * m[c];
            #pragma unroll
            for (int c = 0; c < 8; ++c)
                bMid[c * 8 + g] = m[c] * invs;
        }
        __syncthreads();
        for (int f = 1; f <= 3; ++f) {     // ---- down: one pass per level ----
            int cnt = (f == 1) ? 3 : (f == 2 ? 9 : 27);
            int cl0 = (f == 1) ? 1 : (f == 2 ? 4 : 13);
            int pl0 = (f == 1) ? 0 : (f == 2 ? 1 : 4);
            for (int base = 0; base < cnt; base += 16) {
                int ci = base + vn;
                if (ci < cnt) {
                    int p = ci % 3;
                    int ps = (pl0 + ci / 3) * 64 + g;
                    float r[8];
                    #pragma unroll
                    for (int i = 0; i < 8; ++i) r[i] = bMid[ps + i * 8];
                    float bj[8]; float sv = 0.f;
                    if (f == 3) {
                        const float* src = b3 + (tm * 27 + ci) * 64 + g;
                        #pragma unroll
                        for (int j = 0; j < 8; ++j) bj[j] = src[j * 8];
                    } else {
                        int co = (cl0 + ci) * 64 + g;
                        #pragma unroll
                        for (int j = 0; j < 8; ++j) bj[j] = bMid[co + j * 8];
                        sv = sMs[(cl0 + ci) * 8 + g];
                    }
                    float Bmv[8];
                    bm_row(pBmg, x[xb + cl0 + ci], Bmv);
                    float ev[8]; float esum = 0.f, lg = 0.f;
                    dn_body(r, bj, sSP[p * 8 + g],
                            &sAg[(g * 3 + p) * kAS], &sLAg[(g * 3 + p) * kAS],
                            ev, esum, lg);
                    lg = fmaf(esum, sLSP[p * 8 + g], lg);
                    #pragma unroll
                    for (int c = 0; c < 8; ++c)
                        lg = fmaf(ev[c], Bmv[c], lg);
                    if (f == 3) {
                        #pragma unroll
                        for (int j = 0; j < 8; ++j)
                            AGENT_ST(&e3[(tm * 27 + ci) * 64 + j * 8 + g], ev[j]);
                    } else {
                        int co = (cl0 + ci) * 64 + g;
                        #pragma unroll
                        for (int j = 0; j < 8; ++j)
                            bMid[co + j * 8] =
                                ev[j] * Bmv[j] * __builtin_amdgcn_rcpf(bj[j] * sv);
                    }
                    ellm += lg;
                }
            }
            __syncthreads();
        }
        ellm += __shfl_xor(ellm, 8);
        ellm += __shfl_xor(ellm, 16);
        ellm += __shfl_xor(ellm, 32);
        if (n == 0) atomicAdd(&out[tm * 8 + g], -ellm);
        __builtin_amdgcn_s_waitcnt(0);
        __syncthreads();
        if (ttid == 0) AGENT_ST(&trFlg[tm * 32], kMAGIC2);
    }
}

} // namespace

extern "C" void kernel_launch(void* const* d_in, const int* in_sizes, int n_in,
                              void* d_out, int out_size, void* d_ws, size_t ws_size,
                              hipStream_t stream) {
    const float* lamA  = (const float*)d_in[0];
    const float* lamB  = (const float*)d_in[1];
    const float* lamPi = (const float*)d_in[2];
    const float* lamSP = (const float*)d_in[3];
    const int*   x     = (const int*)d_in[4];
    float* out = (float*)d_out;
    unsigned* sy  = (unsigned*)d_ws;        // sync area (32 KB)
    float* bmG = (float*)d_ws + 8192;       // 8192 floats [g][m][c]
    float* b3  = bmG + 8192;                // 1728*64, rows [c][g]
    float* e3  = b3 + 1728 * 64;            // 1728*64, rows [c][g]

    fused<<<dim3(896), dim3(256), 0, stream>>>(
        lamA, lamB, lamPi, lamSP, x, out, sy, bmG, b3, e3);
}

// Round 8
// 163.449 us; speedup vs baseline: 1.2229x; 1.2229x over previous
//
#include <hip/hip_runtime.h>
#include <hip/hip_fp16.h>

// PosteriorHiddenTreeMarkovModel — MI355X / gfx950
// R21 = R19 structure, producers-first dispatch order, __launch_bounds__(256,2).
// Post-mortem R20 (FAIL, absmax 9.75): only delta vs passing R19 was the
// register bound -> failure is occupancy-dependent. The R19/R20 grid put
// consumers (subtree blocks 0..863) BEFORE producers (mid blocks 864..895).
// R19's forced VGPR=64 kept all 896 blocks resident -> worked. With (256,2)
// the allocator was free; if VGPR >128, capacity 3 blocks/CU = 768 < 896 ->
// launch-0: resident subtree blocks wait on trFlg that only a NOT-YET-
// DISPATCHED mid can set -> spin-timeouts -> garbage e3 -> absmax 9.75.
// Fix: mid blocks now at blockIdx 0..31 (resident from round 1), subtree
// blocks 32..895. Any dispatched consumer finds its producer running; mid's
// trCnt wait is progress-safe under rounds (resident trees complete ->
// retire -> free slots). Protocol correct under ANY residency; rounds can
// only cost speed. Keep (256,2): bodies need ~96 VGPR (R13-R15), no spill.
// Structure (from R19): 864 subtree blocks, 256 thr = 2 teams x 2 waves,
// team = one subtree, 16 node-lanes/iter => serial passes 26 -> 15.
// 32 mid blocks: 2 teams, each one tree's mid; fp32 bMid aliased into bW.
// bmG [g][m][c] vector rows; b3/e3 [c][g] (R16's [g][c] was 8x write-amp).
// R18 lesson: no ILP pairing (spills). R17 lesson: avoid grid > residency
// for perf; now also PROVEN harmless for correctness by this ordering.

namespace {

constexpr int kNPT = 3280;
constexpr int kRS  = 72;   // subtree record stride: 64 beta + 8 pre-norm sums
constexpr int kAS  = 68;   // A row stride per (g,p)
constexpr int kMidBlocks = 32;   // blocks 0..31: mid; 32..895: subtrees
constexpr unsigned kMAGIC  = 0x13579BDFu;
constexpr unsigned kMAGIC2 = 0x2468ACEFu;
__device__ __constant__ int LO[6] = {0, 1, 4, 13, 40, 121};
__device__ __constant__ int P3[5] = {1, 3, 9, 27, 81};

#define AGENT_LD(p)    __hip_atomic_load((p), __ATOMIC_RELAXED, __HIP_MEMORY_SCOPE_AGENT)
#define AGENT_ST(p, v) __hip_atomic_store((p), (v), __ATOMIC_RELAXED, __HIP_MEMORY_SCOPE_AGENT)

// Load the 8-float Bm row for (g, xv): pBmg = bmG + g*1024, row at xv*8.
__device__ __forceinline__ void bm_row(const float* __restrict__ pBmg, int xv,
                                       float* m)
{
    const float4 r0 = *(const float4*)(pBmg + (xv << 3));
    const float4 r1 = *(const float4*)(pBmg + (xv << 3) + 4);
    m[0] = r0.x; m[1] = r0.y; m[2] = r0.z; m[3] = r0.w;
    m[4] = r1.x; m[5] = r1.y; m[6] = r1.z; m[7] = r1.w;
}

__device__ __forceinline__ void leaf_beta(const float* __restrict__ sPi,
                                          const float* __restrict__ pBmg,
                                          int p, int xv, int g, float* b)
{
    float m[8];
    bm_row(pBmg, xv, m);
    float s = 0.f;
    #pragma unroll
    for (int c = 0; c < 8; ++c) {
        b[c] = sPi[(c * 3 + p) * 8 + g] * m[c];
        s += b[c];
    }
    float ig = __builtin_amdgcn_rcpf(s);
    #pragma unroll
    for (int c = 0; c < 8; ++c) b[c] *= ig;
}

// acc[i] *= Bm row; returns pre-norm sum
__device__ __forceinline__ float norm_mul(const float* __restrict__ pBmg,
                                          int xv, float* acc)
{
    float m[8];
    bm_row(pBmg, xv, m);
    float s = 0.f;
    #pragma unroll
    for (int i = 0; i < 8; ++i) { acc[i] *= m[i]; s += acc[i]; }
    return s;
}

// acc[i] += (spg*bj[j]) * A[i][j] over j; A row via 2x b128 per j
__device__ __forceinline__ void matvec_acc(const float* __restrict__ arow,
                                           const float* __restrict__ bj,
                                           float spg, float* acc)
{
    #pragma unroll
    for (int j = 0; j < 8; ++j) {
        float4 a0 = *(const float4*)(arow + j * 8);
        float4 a1 = *(const float4*)(arow + j * 8 + 4);
        float cjv = spg * bj[j];
        acc[0] = fmaf(a0.x, cjv, acc[0]); acc[1] = fmaf(a0.y, cjv, acc[1]);
        acc[2] = fmaf(a0.z, cjv, acc[2]); acc[3] = fmaf(a0.w, cjv, acc[3]);
        acc[4] = fmaf(a1.x, cjv, acc[4]); acc[5] = fmaf(a1.y, cjv, acc[5]);
        acc[6] = fmaf(a1.z, cjv, acc[6]); acc[7] = fmaf(a1.w, cjv, acc[7]);
    }
}

// down-pass inner: ev[j] = spg*bj[j]*dot(r,A_j); lg += spg*bj[j]*dot(r,AlogA_j)
__device__ __forceinline__ void dn_body(const float* r, const float* bj, float spg,
                                        const float* __restrict__ arow,
                                        const float* __restrict__ lrow,
                                        float* ev, float& esum, float& lg)
{
    #pragma unroll
    for (int j = 0; j < 8; ++j) {
        float4 a0 = *(const float4*)(arow + j * 8);
        float4 a1 = *(const float4*)(arow + j * 8 + 4);
        float4 l0 = *(const float4*)(lrow + j * 8);
        float4 l1 = *(const float4*)(lrow + j * 8 + 4);
        float s1 = r[0] * a0.x; s1 = fmaf(r[1], a0.y, s1);
        s1 = fmaf(r[2], a0.z, s1); s1 = fmaf(r[3], a0.w, s1);
        s1 = fmaf(r[4], a1.x, s1); s1 = fmaf(r[5], a1.y, s1);
        s1 = fmaf(r[6], a1.z, s1); s1 = fmaf(r[7], a1.w, s1);
        float s2 = r[0] * l0.x; s2 = fmaf(r[1], l0.y, s2);
        s2 = fmaf(r[2], l0.z, s2); s2 = fmaf(r[3], l0.w, s2);
        s2 = fmaf(r[4], l1.x, s2); s2 = fmaf(r[5], l1.y, s2);
        s2 = fmaf(r[6], l1.z, s2); s2 = fmaf(r[7], l1.w, s2);
        float bs = spg * bj[j];
        ev[j] = bs * s1;
        lg    = fmaf(bs, s2, lg);
        esum += ev[j];
    }
}

__global__ __launch_bounds__(256, 2)
void fused(const float* __restrict__ lamA, const float* __restrict__ lamB,
           const float* __restrict__ lamPi, const float* __restrict__ lamSP,
           const int* __restrict__ x, float* __restrict__ out,
           unsigned* __restrict__ sy, float* __restrict__ bmG,
           float* __restrict__ b3, float* __restrict__ e3)
{
    const int tid = threadIdx.x, w = tid >> 6, lane = tid & 63;
    const int n = lane >> 3, g = lane & 7;
    const int team = w >> 1, wv = w & 1;
    const int vn = (wv << 3) + n;      // 16 node-lanes per team
    const int ttid = tid & 127;        // team-local tid
    __shared__ __align__(16) float sAg[24 * kAS];   // A    [g][p][j][i]
    __shared__ __align__(16) float sLAg[24 * kAS];  // AlogA same layout
    __shared__ float sPi[192], sLPi[192], sSP[24], sLSP[24];
    __shared__ float bW[2][40 * kRS];               // per-team subtree records
    __shared__ unsigned char xW[2][124];
    unsigned* trCnt = sy + 32;
    unsigned* trFlg = sy + 2080;

    // ---- init gate ----
    if (tid == 0) {
        if (blockIdx.x == 0) {
            for (int i = 0; i < 64; ++i) AGENT_ST(&trCnt[i * 32], 0u);
            __builtin_amdgcn_s_waitcnt(0);
            AGENT_ST(&sy[0], kMAGIC);
        }
        unsigned long sp = 0;
        while (AGENT_LD(&sy[0]) != kMAGIC) {
            if (++sp > (1UL << 24)) break;
            __builtin_amdgcn_s_sleep(2);
        }
    }
    __syncthreads();

    // ================= phase 0: parameters =================
    if (blockIdx.x == 0) {   // Bm softmax -> bmG [g][m][c] + flag
        float* rr = &bW[0][0];
        int row = tid >> 2, part = tid & 3;
        int c = row >> 3, gg = row & 7, m0 = part * 32;
        float mx = -1e30f;
        for (int mm = 0; mm < 32; ++mm)
            mx = fmaxf(mx, lamB[(c * 128 + m0 + mm) * 8 + gg]);
        rr[tid] = mx;
        __syncthreads();
        float m4 = fmaxf(fmaxf(rr[row * 4], rr[row * 4 + 1]),
                         fmaxf(rr[row * 4 + 2], rr[row * 4 + 3]));
        float s = 0.f;
        for (int mm = 0; mm < 32; ++mm)
            s += expf(lamB[(c * 128 + m0 + mm) * 8 + gg] - m4);
        rr[256 + tid] = s;
        __syncthreads();
        float stot = rr[256 + row * 4] + rr[256 + row * 4 + 1]
                   + rr[256 + row * 4 + 2] + rr[256 + row * 4 + 3];
        float inv = 1.f / stot;
        for (int mm = 0; mm < 32; ++mm)
            AGENT_ST(&bmG[(gg * 128 + m0 + mm) * 8 + c],
                     expf(lamB[(c * 128 + m0 + mm) * 8 + gg] - m4) * inv);
        __syncthreads();
        if (tid == 0) AGENT_ST(&sy[4], kMAGIC2);
    }
    for (int col = tid; col < 192; col += 256) {   // A softmax over i -> g-major
        int j = col / 24; int rem = col - j * 24; int p = rem >> 3; int gg = rem & 7;
        float v[8]; float mx = -1e30f;
        #pragma unroll
        for (int i = 0; i < 8; ++i) {
            v[i] = lamA[((i * 8 + j) * 3 + p) * 8 + gg];
            mx = fmaxf(mx, v[i]);
        }
        float s = 0.f;
        #pragma unroll
        for (int i = 0; i < 8; ++i) { v[i] = expf(v[i] - mx); s += v[i]; }
        float inv = 1.f / s;
        int base = (gg * 3 + p) * kAS + j * 8;
        #pragma unroll
        for (int i = 0; i < 8; ++i) {
            float sm = v[i] * inv;
            sAg[base + i]  = sm;
            sLAg[base + i] = sm * logf(sm);
        }
    }
    for (int col = tid; col < 24; col += 256) {    // Pi softmax over c
        int p = col >> 3; int gg = col & 7;
        float v[8]; float mx = -1e30f;
        #pragma unroll
        for (int c = 0; c < 8; ++c) {
            v[c] = lamPi[(c * 3 + p) * 8 + gg];
            mx = fmaxf(mx, v[c]);
        }
        float s = 0.f;
        #pragma unroll
        for (int c = 0; c < 8; ++c) { v[c] = expf(v[c] - mx); s += v[c]; }
        float inv = 1.f / s;
        #pragma unroll
        for (int c = 0; c < 8; ++c) {
            int idx = (c * 3 + p) * 8 + gg;
            float sm = v[c] * inv;
            sPi[idx]  = sm;
            sLPi[idx] = logf(sm);
        }
    }
    if (tid < 8) {                                 // SP softmax over p
        int gg = tid;
        float v0 = lamSP[gg], v1 = lamSP[8 + gg], v2 = lamSP[16 + gg];
        float mx = fmaxf(v0, fmaxf(v1, v2));
        float e0 = expf(v0 - mx), e1 = expf(v1 - mx), e2 = expf(v2 - mx);
        float inv = 1.f / (e0 + e1 + e2);
        sSP[gg] = e0 * inv; sSP[8 + gg] = e1 * inv; sSP[16 + gg] = e2 * inv;
        sLSP[gg] = logf(e0 * inv); sLSP[8 + gg] = logf(e1 * inv); sLSP[16 + gg] = logf(e2 * inv);
    }
    if (tid == 0) {        // Bm gate: one fence per block per launch
        unsigned long sp = 0;
        while (AGENT_LD(&sy[4]) != kMAGIC2) {
            if (++sp > (1UL << 24)) break;
            __builtin_amdgcn_s_sleep(2);
        }
        __threadfence();
    }
    __syncthreads();

    const float* pBmg = bmG + (g << 10);   // per-lane Bm row base [g][m][c]
    float* bw = &bW[team][0];

    if (blockIdx.x >= kMidBlocks) {
        // ============ subtree block: 2 teams, each one subtree ============
        unsigned char* xw = &xW[team][0];
        const int sIdx = (blockIdx.x - kMidBlocks) * 2 + team;
        const int t = sIdx / 27, q = sIdx - t * 27;
        const int xb = t * kNPT;

        for (int u = ttid; u < 121; u += 128) {
            int gx;
            if (u == 0)       gx = 13 + q;
            else if (u < 4)   gx = 40  + q * 3  + (u - 1);
            else if (u < 13)  gx = 121 + q * 9  + (u - 4);
            else if (u < 40)  gx = 364 + q * 27 + (u - 13);
            else              gx = 1093 + q * 81 + (u - 40);
            xw[u] = (unsigned char)x[xb + gx];
        }
        __syncthreads();

        // ---- up-pass: 16 node-lanes per team ----
        for (int e = 3; e >= 0; --e) {
            int cnt = P3[e];
            for (int base = 0; base < cnt; base += 16) {
                int node = base + vn;
                if (node < cnt) {
                    float acc[8];
                    #pragma unroll
                    for (int i = 0; i < 8; ++i) acc[i] = 0.f;
                    #pragma unroll
                    for (int k = 0; k < 3; ++k) {
                        float bj[8];
                        if (e == 3) {
                            leaf_beta(sPi, pBmg, k, xw[40 + 3 * node + k], g, bj);
                        } else {
                            int co = (LO[e + 1] + 3 * node + k) * kRS + g;
                            #pragma unroll
                            for (int j = 0; j < 8; ++j) bj[j] = bw[co + j * 8];
                        }
                        matvec_acc(&sAg[(g * 3 + k) * kAS], bj, sSP[k * 8 + g], acc);
                    }
                    if (e == 0) {
                        #pragma unroll
                        for (int i = 0; i < 8; ++i) bw[i * 8 + g] = acc[i];  // raw tb root
                        float s = norm_mul(pBmg, xw[0], acc);
                        float ig = __builtin_amdgcn_rcpf(s);
                        #pragma unroll
                        for (int i = 0; i < 8; ++i)
                            AGENT_ST(&b3[sIdx * 64 + i * 8 + g], acc[i] * ig);
                    } else {
                        int slot = LO[e] + node;
                        float s = norm_mul(pBmg, xw[slot], acc);
                        float ig = __builtin_amdgcn_rcpf(s);
                        int bo = slot * kRS + g;
                        #pragma unroll
                        for (int i = 0; i < 8; ++i) bw[bo + i * 8] = acc[i] * ig;
                        bw[slot * kRS + 64 + g] = s;
                    }
                }
            }
            __syncthreads();
        }
        __builtin_amdgcn_s_waitcnt(0);
        if (ttid == 0)
            __hip_atomic_fetch_add(&trCnt[t * 32], 1u, __ATOMIC_RELAXED,
                                   __HIP_MEMORY_SCOPE_AGENT);

        // ---- wait for mid flag (stale-fast), then down-pass ----
        {
            unsigned long sp = 0;
            while (AGENT_LD(&trFlg[t * 32]) != kMAGIC2) {
                if (++sp > (1UL << 22)) break;
                __builtin_amdgcn_s_sleep(1);
            }
        }
        if (wv == 0)
            bw[lane] = AGENT_LD(&e3[sIdx * 64 + lane])
                       * __builtin_amdgcn_rcpf(bw[lane]);
        __syncthreads();

        float ell = 0.f;
        for (int e = 1; e <= 4; ++e) {
            int cnt = P3[e], pl0 = LO[e - 1];
            for (int base = 0; base < cnt; base += 16) {
                int ci = base + vn;
                if (ci < cnt) {
                    int p = ci % 3;
                    int ps = (pl0 + ci / 3) * kRS + g;
                    float r[8];
                    #pragma unroll
                    for (int i = 0; i < 8; ++i) r[i] = bw[ps + i * 8];
                    float bj[8], Bmv[8]; float sv = 0.f;
                    if (e == 4) {
                        bm_row(pBmg, xw[40 + ci], Bmv);   // one load, used twice
                        float s = 0.f;
                        #pragma unroll
                        for (int c = 0; c < 8; ++c) {
                            bj[c] = sPi[(c * 3 + p) * 8 + g] * Bmv[c];
                            s += bj[c];
                        }
                        float ig = __builtin_amdgcn_rcpf(s);
                        #pragma unroll
                        for (int c = 0; c < 8; ++c) bj[c] *= ig;
                    } else {
                        int slot = LO[e] + ci;
                        bm_row(pBmg, xw[slot], Bmv);
                        int co = slot * kRS + g;
                        #pragma unroll
                        for (int j = 0; j < 8; ++j) bj[j] = bw[co + j * 8];
                        sv = bw[slot * kRS + 64 + g];
                    }
                    float ev[8]; float esum = 0.f, lg = 0.f;
                    dn_body(r, bj, sSP[p * 8 + g],
                            &sAg[(g * 3 + p) * kAS], &sLAg[(g * 3 + p) * kAS],
                            ev, esum, lg);
                    lg = fmaf(esum, sLSP[p * 8 + g], lg);
                    #pragma unroll
                    for (int c = 0; c < 8; ++c) lg = fmaf(ev[c], Bmv[c], lg);
                    if (e < 4) {
                        int slot = LO[e] + ci;
                        int co = slot * kRS + g;
                        #pragma unroll
                        for (int j = 0; j < 8; ++j)
                            bw[co + j * 8] = ev[j] * Bmv[j]
                                * __builtin_amdgcn_rcpf(bj[j] * sv);
                    } else {
                        #pragma unroll
                        for (int c = 0; c < 8; ++c)
                            lg = fmaf(ev[c], sLPi[(c * 3 + p) * 8 + g], lg);
                    }
                    ell += lg;
                }
            }
            __syncthreads();
        }

        ell += __shfl_xor(ell, 8);
        ell += __shfl_xor(ell, 16);
        ell += __shfl_xor(ell, 32);
        if (n == 0) atomicAdd(&out[t * 8 + g], -ell);
        return;
    }

    // ============ mid block (idx 0..31): 2 teams, each one tree's mid =====
    {
        const int tm = blockIdx.x * 2 + team;
        const int xb = tm * kNPT;
        float* bMid = bw;               // 13*64 fp32, aliased into record
        float* sMs  = bw + 13 * 64;     // 13*8 pre-norm sums

        {
            unsigned long sp = 0;
            while (AGENT_LD(&trCnt[tm * 32]) < 27u) {
                if (++sp > (1UL << 22)) break;
                __builtin_amdgcn_s_sleep(1);
            }
        }
        __threadfence();   // one invalidate; b3 then read via cached loads
        __syncthreads();

        float ellm = 0.f;

        for (int f = 2; f >= 0; --f) {     // ---- up: one pass per level ----
            int cnt = (f == 2) ? 9 : (f == 1 ? 3 : 1);
            int pl0 = (f == 2) ? 4 : (f == 1 ? 1 : 0);
            int cl0 = (f == 1) ? 4 : 1;
            int pi = vn;
            if (pi < cnt) {
                float acc[8];
                #pragma unroll
                for (int i = 0; i < 8; ++i) acc[i] = 0.f;
                #pragma unroll
                for (int k = 0; k < 3; ++k) {
                    float bj[8];
                    if (f == 2) {
                        const float* src = b3 + (tm * 27 + 3 * pi + k) * 64 + g;
                        #pragma unroll
                        for (int j = 0; j < 8; ++j) bj[j] = src[j * 8];
                    } else {
                        int co = (cl0 + 3 * pi + k) * 64 + g;
                        #pragma unroll
                        for (int j = 0; j < 8; ++j) bj[j] = bMid[co + j * 8];
                    }
                    matvec_acc(&sAg[(g * 3 + k) * kAS], bj, sSP[k * 8 + g], acc);
                }
                int slot = pl0 + pi;
                float s = norm_mul(pBmg, x[xb + slot], acc);
                float ig = __builtin_amdgcn_rcpf(s);
                int bo = slot * 64 + g;
                #pragma unroll
                for (int i = 0; i < 8; ++i) bMid[bo + i * 8] = acc[i] * ig;
                sMs[slot * 8 + g] = s;
            }
            __syncthreads();
        }
        if (wv == 0 && n == 0) {   // root: ell Bm term; slot0 := r = Bm/s
            float m[8];
            bm_row(pBmg, x[xb], m);
            float invs = __builtin_amdgcn_rcpf(sMs[g]);
            #pragma unroll
            for (int c = 0; c < 8; ++c)
                ellm += bMid[c * 8 + g] * m[c];
            #pragma unroll
            for (int c = 0; c < 8; ++c)
                bMid[c * 8 + g] = m[c] * invs;
        }
        __syncthreads();
        for (int f = 1; f <= 3; ++f) {     // ---- down: one pass per level ----
            int cnt = (f == 1) ? 3 : (f == 2 ? 9 : 27);
            int cl0 = (f == 1) ? 1 : (f == 2 ? 4 : 13);
            int pl0 = (f == 1) ? 0 : (f == 2 ? 1 : 4);
            for (int base = 0; base < cnt; base += 16) {
                int ci = base + vn;
                if (ci < cnt) {
                    int p = ci % 3;
                    int ps = (pl0 + ci / 3) * 64 + g;
                    float r[8];
                    #pragma unroll
                    for (int i = 0; i < 8; ++i) r[i] = bMid[ps + i * 8];
                    float bj[8]; float sv = 0.f;
                    if (f == 3) {
                        const float* src = b3 + (tm * 27 + ci) * 64 + g;
                        #pragma unroll
                        for (int j = 0; j < 8; ++j) bj[j] = src[j * 8];
                    } else {
                        int co = (cl0 + ci) * 64 + g;
                        #pragma unroll
                        for (int j = 0; j < 8; ++j) bj[j] = bMid[co + j * 8];
                        sv = sMs[(cl0 + ci) * 8 + g];
                    }
                    float Bmv[8];
                    bm_row(pBmg, x[xb + cl0 + ci], Bmv);
                    float ev[8]; float esum = 0.f, lg = 0.f;
                    dn_body(r, bj, sSP[p * 8 + g],
                            &sAg[(g * 3 + p) * kAS], &sLAg[(g * 3 + p) * kAS],
                            ev, esum, lg);
                    lg = fmaf(esum, sLSP[p * 8 + g], lg);
                    #pragma unroll
                    for (int c = 0; c < 8; ++c)
                        lg = fmaf(ev[c], Bmv[c], lg);
                    if (f == 3) {
                        #pragma unroll
                        for (int j = 0; j < 8; ++j)
                            AGENT_ST(&e3[(tm * 27 + ci) * 64 + j * 8 + g], ev[j]);
                    } else {
                        int co = (cl0 + ci) * 64 + g;
                        #pragma unroll
                        for (int j = 0; j < 8; ++j)
                            bMid[co + j * 8] =
                                ev[j] * Bmv[j] * __builtin_amdgcn_rcpf(bj[j] * sv);
                    }
                    ellm += lg;
                }
            }
            __syncthreads();
        }
        ellm += __shfl_xor(ellm, 8);
        ellm += __shfl_xor(ellm, 16);
        ellm += __shfl_xor(ellm, 32);
        if (n == 0) atomicAdd(&out[tm * 8 + g], -ellm);
        __builtin_amdgcn_s_waitcnt(0);
        __syncthreads();
        if (ttid == 0) AGENT_ST(&trFlg[tm * 32], kMAGIC2);
    }
}

} // namespace

extern "C" void kernel_launch(void* const* d_in, const int* in_sizes, int n_in,
                              void* d_out, int out_size, void* d_ws, size_t ws_size,
                              hipStream_t stream) {
    const float* lamA  = (const float*)d_in[0];
    const float* lamB  = (const float*)d_in[1];
    const float* lamPi = (const float*)d_in[2];
    const float* lamSP = (const float*)d_in[3];
    const int*   x     = (const int*)d_in[4];
    float* out = (float*)d_out;
    unsigned* sy  = (unsigned*)d_ws;        // sync area (32 KB)
    float* bmG = (float*)d_ws + 8192;       // 8192 floats [g][m][c]
    float* b3  = bmG + 8192;                // 1728*64, rows [c][g]
    float* e3  = b3 + 1728 * 64;            // 1728*64, rows [c][g]

    fused<<<dim3(896), dim3(256), 0, stream>>>(
        lamA, lamB, lamPi, lamSP, x, out, sy, bmG, b3, e3);
}